// Round 1
// 481.004 us; speedup vs baseline: 1.0609x; 1.0609x over previous
//
#include <hip/hip_runtime.h>
#include <hip/hip_fp16.h>

// BN scale constant: 1/sqrt(1+1e-5)
#define RSQ_BN 0.9999950000374997f

typedef _Float16 f16x8 __attribute__((ext_vector_type(8)));
typedef float f32x4 __attribute__((ext_vector_type(4)));

union H8u { uint4 u4; __half h[8]; };

__device__ __forceinline__ float leaky02(float x) { return x > 0.f ? x : 0.2f * x; }

__device__ __forceinline__ float4 ld4(const float* p) {
    return *reinterpret_cast<const float4*>(p);
}
__device__ __forceinline__ void st4(float* p, float4 v) {
    *reinterpret_cast<float4*>(p) = v;
}
__device__ __forceinline__ void ld8(float* d, const float* p) {
    float4 u = ld4(p), v = ld4(p + 4);
    d[0] = u.x; d[1] = u.y; d[2] = u.z; d[3] = u.w;
    d[4] = v.x; d[5] = v.y; d[6] = v.z; d[7] = v.w;
}
__device__ __forceinline__ void st8(float* p, const float* v) {
    st4(p, make_float4(v[0], v[1], v[2], v[3]));
    st4(p + 4, make_float4(v[4], v[5], v[6], v[7]));
}

// ---------------- CSR build ----------------

__global__ void hist_k(const int* __restrict__ edst, int* __restrict__ cnt, int E, int EN) {
    int i = blockIdx.x * 256 + threadIdx.x;
    if (i >= EN) return;
    int d = (i < E) ? edst[i] : (i - E);   // self-loop for i>=E
    atomicAdd(&cnt[d], 1);
}

__global__ __launch_bounds__(256)
void scanA_k(const int* __restrict__ cnt, int* __restrict__ rowptr,
             int* __restrict__ bsum, int n) {
    __shared__ int sh[256];
    int t = threadIdx.x;
    int i = blockIdx.x * 256 + t;
    int v = (i < n) ? cnt[i] : 0;
    sh[t] = v;
    __syncthreads();
#pragma unroll
    for (int off = 1; off < 256; off <<= 1) {
        int u = 0;
        if (t >= off) u = sh[t - off];
        __syncthreads();
        sh[t] += u;
        __syncthreads();
    }
    if (i < n) rowptr[i] = sh[t] - v;
    if (t == 255) bsum[blockIdx.x] = sh[255];
}

__global__ __launch_bounds__(256)
void scanB_k(int* __restrict__ bsum, int nb) {
    __shared__ int sh[256];
    int t = threadIdx.x;
    int v = (t < nb) ? bsum[t] : 0;
    sh[t] = v;
    __syncthreads();
#pragma unroll
    for (int off = 1; off < 256; off <<= 1) {
        int u = 0;
        if (t >= off) u = sh[t - off];
        __syncthreads();
        sh[t] += u;
        __syncthreads();
    }
    if (t < nb) bsum[t] = sh[t] - v;
}

__global__ __launch_bounds__(256)
void scanC_k(const int* __restrict__ cnt, const int* __restrict__ bsum,
             int* __restrict__ rowptr, int* __restrict__ cursor,
             float* __restrict__ dis, int n, int EN) {
    int i = blockIdx.x * 256 + threadIdx.x;
    if (i < n) {
        int r = rowptr[i] + bsum[blockIdx.x];
        rowptr[i] = r;
        cursor[i] = r;
        dis[i] = rsqrtf((float)cnt[i]);
    }
    if (i == 0) rowptr[n] = EN;
}

__global__ void scatter_k(const int* __restrict__ esrc, const int* __restrict__ edst,
                          int* __restrict__ cursor, int* __restrict__ colidx, int E, int EN) {
    int i = blockIdx.x * 256 + threadIdx.x;
    if (i >= EN) return;
    int s, d;
    if (i < E) { s = esrc[i]; d = edst[i]; }
    else       { s = i - E; d = s; }
    int pos = atomicAdd(&cursor[d], 1);
    colidx[pos] = s;
}

// ---------------- all-weights transpose + fp16 convert (one launch) ----------------
// dst layout [M][K] fp16 from src [K][M] fp32.

__global__ void wtx_all_k(const float* __restrict__ gcn_in_w, const float* __restrict__ gcn_res_w,
                          const float* __restrict__ gat_in_w,
                          const float* __restrict__ gcn_w, const float* __restrict__ gat_w,
                          const float* __restrict__ gcn_c1w, const float* __restrict__ gat_c1w,
                          const float* __restrict__ gcn_c3w, const float* __restrict__ gat_c3w,
                          const float* __restrict__ fin_w,
                          const float* __restrict__ gcn_c2w, const float* __restrict__ gat_c2w,
                          __half* __restrict__ WTin, __half* __restrict__ WTg,
                          __half* __restrict__ WTa, __half* __restrict__ WTc1,
                          __half* __restrict__ WTc3, __half* __restrict__ WTfin,
                          __half* __restrict__ WTc2) {
    int idx = blockIdx.x * 256 + threadIdx.x;
    const float* src;
    __half* dst;
    int K, M, o;
    if (idx < 24576) {                      // 3x (64x128) input mats
        int mi = idx >> 13; o = idx & 8191;
        src = mi == 0 ? gcn_in_w : (mi == 1 ? gcn_res_w : gat_in_w);
        dst = WTin + mi * 8192; K = 64; M = 128;
    } else if (idx < 73728) {               // 3x (128x128) gcn layer mats
        int r = idx - 24576; int mi = r >> 14; o = r & 16383;
        src = gcn_w + mi * 16384; dst = WTg + mi * 16384; K = 128; M = 128;
    } else if (idx < 122880) {              // 3x (128x128) gat layer mats
        int r = idx - 73728; int mi = r >> 14; o = r & 16383;
        src = gat_w + mi * 16384; dst = WTa + mi * 16384; K = 128; M = 128;
    } else if (idx < 139264) {              // 2x (128x64) c1 mats
        int r = idx - 122880; int mi = r >> 13; o = r & 8191;
        src = mi ? gat_c1w : gcn_c1w; dst = WTc1 + mi * 8192; K = 128; M = 64;
    } else if (idx < 147456) {              // 2x (32x128) c3 mats
        int r = idx - 139264; int mi = r >> 12; o = r & 4095;
        src = mi ? gat_c3w : gcn_c3w; dst = WTc3 + mi * 4096; K = 32; M = 128;
    } else if (idx < 155648) {              // fin (128x64)
        o = idx - 147456; src = fin_w; dst = WTfin; K = 128; M = 64;
    } else if (idx < 159744) {              // 2x (64x32) c2 mats
        int r = idx - 155648; int mi = r >> 11; o = r & 2047;
        src = mi ? gat_c2w : gcn_c2w; dst = WTc2 + mi * 2048; K = 64; M = 32;
    } else return;
    int mcol = o / K, k = o - mcol * K;
    dst[o] = (__half)src[k * M + mcol];
}

// ---------------- MFMA dense kernels ----------------

__device__ __forceinline__ f16x8 mk_af(const float* xr, int kb) {
    float4 v0 = ld4(xr + kb), v1 = ld4(xr + kb + 4);
    f16x8 af;
    af[0] = (_Float16)v0.x; af[1] = (_Float16)v0.y;
    af[2] = (_Float16)v0.z; af[3] = (_Float16)v0.w;
    af[4] = (_Float16)v1.x; af[5] = (_Float16)v1.y;
    af[6] = (_Float16)v1.z; af[7] = (_Float16)v1.w;
    return af;
}

// input stage: 3 weight sets, same X (K=64, M=128), bias only, fp32 out
__global__ __launch_bounds__(256)
void mfma_lin3_k(const float* __restrict__ X, const __half* __restrict__ WTin,
                 const float* __restrict__ b0, float* __restrict__ Y0,
                 const float* __restrict__ b1, float* __restrict__ Y1,
                 const float* __restrict__ b2, float* __restrict__ Y2,
                 int n, int gper) {
    constexpr int K = 64, CT = 8;
    int set = blockIdx.x / gper, blk = blockIdx.x % gper;
    const __half* WT = WTin + (size_t)set * 8192;
    const float* bi = set == 0 ? b0 : (set == 1 ? b1 : b2);
    float* Y = set == 0 ? Y0 : (set == 1 ? Y1 : Y2);
    int wave = threadIdx.x >> 6, lane = threadIdx.x & 63;
    int m = lane & 15, quad = lane >> 4;
    int row0 = blk * 64 + wave * 16;
    int arow = min(row0 + m, n - 1);
    const float* xr = X + (size_t)arow * K;
    f32x4 acc[CT];
#pragma unroll
    for (int ct = 0; ct < CT; ++ct) acc[ct] = (f32x4){0.f, 0.f, 0.f, 0.f};
#pragma unroll
    for (int k32 = 0; k32 < K / 32; ++k32) {
        int kb = k32 * 32 + quad * 8;
        f16x8 af = mk_af(xr, kb);
#pragma unroll
        for (int ct = 0; ct < CT; ++ct) {
            f16x8 bf = *reinterpret_cast<const f16x8*>(WT + (size_t)(ct * 16 + m) * K + kb);
            acc[ct] = __builtin_amdgcn_mfma_f32_16x16x32_f16(af, bf, acc[ct], 0, 0, 0);
        }
    }
#pragma unroll
    for (int ct = 0; ct < CT; ++ct) {
        int col = ct * 16 + m;
        float cb = bi[col];
#pragma unroll
        for (int reg = 0; reg < 4; ++reg) {
            int row = row0 + quad * 4 + reg;
            if (row < n) Y[(size_t)row * 128 + col] = acc[ct][reg] + cb;
        }
    }
}

// ---------------- per-layer pair GEMM via MFMA (gcn dis-fold + gat attn dots) ----------------

__global__ __launch_bounds__(256)
void dual128_mfma_k(const float* __restrict__ Xg, const __half* __restrict__ WTg,
                    __half* __restrict__ Yg,
                    const float* __restrict__ Xa, const __half* __restrict__ WTa,
                    __half* __restrict__ Ya,
                    const float* __restrict__ dis,
                    const float* __restrict__ asrc, const float* __restrict__ adst,
                    float* __restrict__ avp, float* __restrict__ bvp,
                    int hh, int n, int gper) {
    bool gat = blockIdx.x >= gper;
    int blk = gat ? blockIdx.x - gper : blockIdx.x;
    const float* X = gat ? Xa : Xg;
    const __half* WT = gat ? WTa : WTg;
    __half* Y = gat ? Ya : Yg;
    int wave = threadIdx.x >> 6;
    int lane = threadIdx.x & 63;
    int m = lane & 15, quad = lane >> 4;
    int row0 = blk * 64 + wave * 16;
    int arow = min(row0 + m, n - 1);
    const float* xr = X + (size_t)arow * 128;
    f32x4 acc[8];
#pragma unroll
    for (int ct = 0; ct < 8; ++ct) acc[ct] = (f32x4){0.f, 0.f, 0.f, 0.f};
#pragma unroll
    for (int k32 = 0; k32 < 4; ++k32) {
        int kb = k32 * 32 + quad * 8;
        f16x8 af = mk_af(xr, kb);
#pragma unroll
        for (int ct = 0; ct < 8; ++ct) {
            f16x8 bf = *reinterpret_cast<const f16x8*>(WT + (size_t)(ct * 16 + m) * 128 + kb);
            acc[ct] = __builtin_amdgcn_mfma_f32_16x16x32_f16(af, bf, acc[ct], 0, 0, 0);
        }
    }
    if (!gat) {
#pragma unroll
        for (int reg = 0; reg < 4; ++reg) {
            int row = row0 + quad * 4 + reg;
            if (row < n) {
                float dv = dis[row];
#pragma unroll
                for (int ct = 0; ct < 8; ++ct)
                    Y[(size_t)row * 128 + ct * 16 + m] = (__half)(acc[ct][reg] * dv);
            }
        }
    } else {
        float cas[8], cad[8];
#pragma unroll
        for (int ct = 0; ct < 8; ++ct) {
            cas[ct] = asrc[ct * 16 + m];
            cad[ct] = adst[ct * 16 + m];
        }
        int ctph = 8 / hh;   // col-tiles per head
#pragma unroll
        for (int reg = 0; reg < 4; ++reg) {
            int row = row0 + quad * 4 + reg;
            bool valid = row < n;
            if (valid) {
#pragma unroll
                for (int ct = 0; ct < 8; ++ct)
                    Y[(size_t)row * 128 + ct * 16 + m] = (__half)acc[ct][reg];
            }
            for (int h = 0; h < hh; ++h) {
                float sa = 0.f, sd = 0.f;
                for (int j = 0; j < ctph; ++j) {
                    int ct = h * ctph + j;
                    sa += acc[ct][reg] * cas[ct];
                    sd += acc[ct][reg] * cad[ct];
                }
                for (int off = 1; off < 16; off <<= 1) {
                    sa += __shfl_xor(sa, off);
                    sd += __shfl_xor(sd, off);
                }
                if (m == 0 && valid) {
                    avp[row * hh + h] = sa;
                    bvp[row * hh + h] = sd;
                }
            }
        }
    }
}

// ---------------- fused sparse aggregation: one row-walk, BOTH tables, 4-edge groups ----------------
// 16 lanes/node, 8 cols (16B fp16) per lane per table; colidx + avp software-pipelined.

__global__ __launch_bounds__(256)
void fused_gather_k(const int* __restrict__ rowptr, const int* __restrict__ colidx,
                    const float* __restrict__ dis,
                    const __half* __restrict__ Tg, const float* __restrict__ gbias,
                    const float* __restrict__ gbng, const float* __restrict__ gbnb,
                    const float* __restrict__ res, float* __restrict__ Yg,
                    const __half* __restrict__ Ta, const float* __restrict__ avp,
                    const float* __restrict__ bvp, const float* __restrict__ abias,
                    const float* __restrict__ abng, const float* __restrict__ abnb,
                    const float* __restrict__ fimp, float* __restrict__ Ya,
                    int n, int hh, int log2C) {
    int idx = blockIdx.x * 256 + threadIdx.x;
    int i = idx >> 4;
    if (i >= n) return;
    int c = (idx & 15) * 8;
    int h = c >> log2C;
    float ad = bvp[i * hh + h];
    int p0 = rowptr[i], p1 = rowptr[i + 1];
    float g[8], a[8];
#pragma unroll
    for (int t = 0; t < 8; ++t) { g[t] = 0.f; a[t] = 0.f; }
    float m = -3.0e38f, s = 0.f;

    int p = p0;
    int nfull = (p1 - p0) >> 2;
    int sx[4]; float av[4];
    if (nfull > 0) {
#pragma unroll
        for (int j = 0; j < 4; ++j) sx[j] = colidx[p + j];
#pragma unroll
        for (int j = 0; j < 4; ++j) av[j] = avp[sx[j] * hh + h];
    }
    for (int gi = 0; gi < nfull; ++gi) {
        // issue the 8 long-latency gathers first
        uint4 qg[4], qa[4];
#pragma unroll
        for (int j = 0; j < 4; ++j)
            qg[j] = *reinterpret_cast<const uint4*>(Tg + (size_t)sx[j] * 128 + c);
#pragma unroll
        for (int j = 0; j < 4; ++j)
            qa[j] = *reinterpret_cast<const uint4*>(Ta + (size_t)sx[j] * 128 + c);
        // prefetch next group's indices AND attention scores while gathers fly
        int pn = p + 4;
        bool more = (gi + 1) < nfull;
        int sn[4]; float avn[4];
#pragma unroll
        for (int j = 0; j < 4; ++j) sn[j] = more ? colidx[pn + j] : 0;
#pragma unroll
        for (int j = 0; j < 4; ++j) avn[j] = avp[sn[j] * hh + h];
        // softmax scalars (fast exp: v_exp_f32)
        float e0 = leaky02(av[0] + ad), e1 = leaky02(av[1] + ad);
        float e2 = leaky02(av[2] + ad), e3 = leaky02(av[3] + ad);
        float mc = fmaxf(fmaxf(e0, e1), fmaxf(e2, e3));
        float mn = fmaxf(m, mc);
        float scale = __expf(m - mn);
        float w0 = __expf(e0 - mn), w1 = __expf(e1 - mn);
        float w2 = __expf(e2 - mn), w3 = __expf(e3 - mn);
        s = s * scale + (w0 + w1 + w2 + w3);
        m = mn;
        // GCN accumulate (cvt+add; fp32 exact)
        {
            H8u k0, k1, k2, k3;
            k0.u4 = qg[0]; k1.u4 = qg[1]; k2.u4 = qg[2]; k3.u4 = qg[3];
#pragma unroll
            for (int t = 0; t < 8; ++t)
                g[t] += __half2float(k0.h[t]) + __half2float(k1.h[t])
                      + __half2float(k2.h[t]) + __half2float(k3.h[t]);
        }
        // GAT online accumulate (fmaf(ext(f16), w, acc) -> v_fma_mix_f32)
        {
            H8u k0, k1, k2, k3;
            k0.u4 = qa[0]; k1.u4 = qa[1]; k2.u4 = qa[2]; k3.u4 = qa[3];
#pragma unroll
            for (int t = 0; t < 8; ++t) {
                float v = a[t] * scale;
                v = fmaf(__half2float(k0.h[t]), w0, v);
                v = fmaf(__half2float(k1.h[t]), w1, v);
                v = fmaf(__half2float(k2.h[t]), w2, v);
                v = fmaf(__half2float(k3.h[t]), w3, v);
                a[t] = v;
            }
        }
        p = pn;
#pragma unroll
        for (int j = 0; j < 4; ++j) { sx[j] = sn[j]; av[j] = avn[j]; }
    }
    for (; p < p1; ++p) {
        int s0 = colidx[p];
        float e0 = leaky02(avp[s0 * hh + h] + ad);
        uint4 qg0 = *reinterpret_cast<const uint4*>(Tg + (size_t)s0 * 128 + c);
        uint4 qa0 = *reinterpret_cast<const uint4*>(Ta + (size_t)s0 * 128 + c);
        float mn = fmaxf(m, e0);
        float scale = __expf(m - mn);
        float w0 = __expf(e0 - mn);
        s = s * scale + w0;
        m = mn;
        H8u kg, ka; kg.u4 = qg0; ka.u4 = qa0;
#pragma unroll
        for (int t = 0; t < 8; ++t) {
            g[t] += __half2float(kg.h[t]);
            a[t] = fmaf(__half2float(ka.h[t]), w0, a[t] * scale);
        }
    }

    // ---- GCN epilogue ----
    {
        float di = dis[i];
        float bb[8], gg[8], nb[8];
        ld8(bb, gbias + c); ld8(gg, gbng + c); ld8(nb, gbnb + c);
        float o[8];
#pragma unroll
        for (int t = 0; t < 8; ++t) {
            float v = g[t] * di + bb[t];
            o[t] = fmaxf(v * (gg[t] * RSQ_BN) + nb[t], 0.f);
        }
        if (res) {
            float rr[8]; ld8(rr, res + (size_t)i * 128 + c);
#pragma unroll
            for (int t = 0; t < 8; ++t) o[t] += rr[t];
        }
        st8(Yg + (size_t)i * 128 + c, o);
    }
    // ---- GAT epilogue ----
    {
        float si = 1.f / (s + 1e-16f);
        float bb[8], gg[8], nb[8];
        ld8(bb, abias + c); ld8(gg, abng + c); ld8(nb, abnb + c);
        float o[8];
#pragma unroll
        for (int t = 0; t < 8; ++t) {
            float v = a[t] * si + bb[t];
            v = v * (gg[t] * RSQ_BN) + nb[t];
            o[t] = v > 0.f ? v : expm1f(v);
        }
        if (fimp) {
            float ff[8]; ld8(ff, fimp + c);
#pragma unroll
            for (int t = 0; t < 8; ++t) o[t] *= ff[t];
        }
        st8(Ya + (size_t)i * 128 + c, o);
    }
}

// ---------------- fused MLP tail: c1 -> c2 -> c3 -> blend -> fin -> bn -> fin2 ----------------
// One block = 64 rows, 4 waves x 16 rows. All intermediates staged in LDS (fp16, conflict-padded).

__global__ __launch_bounds__(256)
void fused_tail_k(const float* __restrict__ Xg, const float* __restrict__ Xa,
                  const __half* __restrict__ WTc1,
                  const float* __restrict__ c1bg, const float* __restrict__ c1ba,
                  const float* __restrict__ cbng, const float* __restrict__ cbnb,
                  const __half* __restrict__ WTc2,
                  const float* __restrict__ c2bg, const float* __restrict__ c2ba,
                  const __half* __restrict__ WTc3,
                  const float* __restrict__ c3bg, const float* __restrict__ c3ba,
                  const __half* __restrict__ WTfin, const float* __restrict__ finb,
                  const float* __restrict__ fbng, const float* __restrict__ fbnb,
                  const float* __restrict__ w2, const float* __restrict__ b2,
                  float* __restrict__ out, int n) {
    // row strides: 88/56/152 halves -> 16B-aligned rows, 2-way-max bank aliasing (free)
    __shared__ alignas(16) __half h1s[2][64][88];
    __shared__ alignas(16) __half h2s[2][64][56];
    __shared__ alignas(16) __half Fs[64][152];
    int wave = threadIdx.x >> 6, lane = threadIdx.x & 63;
    int m = lane & 15, quad = lane >> 4;
    int row0 = blockIdx.x * 64 + wave * 16;
    int lr0 = wave * 16;
    int arow = min(row0 + m, n - 1);

    // ---- S1: X @ c1 (K=128,M=64), relu [+bn for gat] -> h1 ----
#pragma unroll
    for (int br = 0; br < 2; ++br) {
        const float* xr = (br ? Xa : Xg) + (size_t)arow * 128;
        const __half* WT = WTc1 + br * 8192;
        f32x4 acc[4];
#pragma unroll
        for (int ct = 0; ct < 4; ++ct) acc[ct] = (f32x4){0.f, 0.f, 0.f, 0.f};
#pragma unroll
        for (int k32 = 0; k32 < 4; ++k32) {
            int kb = k32 * 32 + quad * 8;
            f16x8 af = mk_af(xr, kb);
#pragma unroll
            for (int ct = 0; ct < 4; ++ct) {
                f16x8 bf = *reinterpret_cast<const f16x8*>(WT + (ct * 16 + m) * 128 + kb);
                acc[ct] = __builtin_amdgcn_mfma_f32_16x16x32_f16(af, bf, acc[ct], 0, 0, 0);
            }
        }
        const float* bi = br ? c1ba : c1bg;
#pragma unroll
        for (int ct = 0; ct < 4; ++ct) {
            int col = ct * 16 + m;
            float cb = bi[col];
            float cg = br ? cbng[col] * RSQ_BN : 1.f;
            float cbb = br ? cbnb[col] : 0.f;
#pragma unroll
            for (int reg = 0; reg < 4; ++reg) {
                float v = fmaxf(acc[ct][reg] + cb, 0.f) * cg + cbb;
                h1s[br][lr0 + quad * 4 + reg][col] = (__half)v;
            }
        }
    }
    __syncthreads();
    // ---- S2: h1 @ c2 (K=64,M=32), relu -> h2 ----
#pragma unroll
    for (int br = 0; br < 2; ++br) {
        f32x4 acc[2];
        acc[0] = (f32x4){0.f, 0.f, 0.f, 0.f};
        acc[1] = (f32x4){0.f, 0.f, 0.f, 0.f};
        const __half* WT = WTc2 + br * 2048;
#pragma unroll
        for (int k32 = 0; k32 < 2; ++k32) {
            int kb = k32 * 32 + quad * 8;
            f16x8 af = *reinterpret_cast<const f16x8*>(&h1s[br][lr0 + m][kb]);
#pragma unroll
            for (int ct = 0; ct < 2; ++ct) {
                f16x8 bf = *reinterpret_cast<const f16x8*>(WT + (ct * 16 + m) * 64 + kb);
                acc[ct] = __builtin_amdgcn_mfma_f32_16x16x32_f16(af, bf, acc[ct], 0, 0, 0);
            }
        }
        const float* bi = br ? c2ba : c2bg;
#pragma unroll
        for (int ct = 0; ct < 2; ++ct) {
            int col = ct * 16 + m;
            float cb = bi[col];
#pragma unroll
            for (int reg = 0; reg < 4; ++reg) {
                float v = fmaxf(acc[ct][reg] + cb, 0.f);
                h2s[br][lr0 + quad * 4 + reg][col] = (__half)v;
            }
        }
    }
    __syncthreads();
    // ---- S3: h2 @ c3 (K=32,M=128), both branches, blend -> F ----
    {
        f32x4 ag[8], aa[8];
#pragma unroll
        for (int ct = 0; ct < 8; ++ct) {
            ag[ct] = (f32x4){0.f, 0.f, 0.f, 0.f};
            aa[ct] = (f32x4){0.f, 0.f, 0.f, 0.f};
        }
        int kb = quad * 8;
        f16x8 afg = *reinterpret_cast<const f16x8*>(&h2s[0][lr0 + m][kb]);
        f16x8 afa = *reinterpret_cast<const f16x8*>(&h2s[1][lr0 + m][kb]);
#pragma unroll
        for (int ct = 0; ct < 8; ++ct) {
            f16x8 bfg = *reinterpret_cast<const f16x8*>(WTc3 + (ct * 16 + m) * 32 + kb);
            f16x8 bfa = *reinterpret_cast<const f16x8*>(WTc3 + 4096 + (ct * 16 + m) * 32 + kb);
            ag[ct] = __builtin_amdgcn_mfma_f32_16x16x32_f16(afg, bfg, ag[ct], 0, 0, 0);
            aa[ct] = __builtin_amdgcn_mfma_f32_16x16x32_f16(afa, bfa, aa[ct], 0, 0, 0);
        }
#pragma unroll
        for (int ct = 0; ct < 8; ++ct) {
            int col = ct * 16 + m;
            float cb = 0.6f * c3bg[col] + 0.4f * c3ba[col];
#pragma unroll
            for (int reg = 0; reg < 4; ++reg) {
                float v = 0.6f * ag[ct][reg] + 0.4f * aa[ct][reg] + cb;
                Fs[lr0 + quad * 4 + reg][col] = (__half)v;
            }
        }
    }
    __syncthreads();
    // ---- S4: F @ fin (K=128,M=64), relu, bn, @fin2 -> out[n,2] ----
    {
        f32x4 acc[4];
#pragma unroll
        for (int ct = 0; ct < 4; ++ct) acc[ct] = (f32x4){0.f, 0.f, 0.f, 0.f};
#pragma unroll
        for (int k32 = 0; k32 < 4; ++k32) {
            int kb = k32 * 32 + quad * 8;
            f16x8 af = *reinterpret_cast<const f16x8*>(&Fs[lr0 + m][kb]);
#pragma unroll
            for (int ct = 0; ct < 4; ++ct) {
                f16x8 bf = *reinterpret_cast<const f16x8*>(WTfin + (ct * 16 + m) * 128 + kb);
                acc[ct] = __builtin_amdgcn_mfma_f32_16x16x32_f16(af, bf, acc[ct], 0, 0, 0);
            }
        }
        float p0[4] = {0.f, 0.f, 0.f, 0.f}, p1[4] = {0.f, 0.f, 0.f, 0.f};
#pragma unroll
        for (int ct = 0; ct < 4; ++ct) {
            int col = ct * 16 + m;
            float cb = finb[col];
            float cg = fbng[col] * RSQ_BN;
            float cbb = fbnb[col];
            float w20 = w2[2 * col], w21 = w2[2 * col + 1];
#pragma unroll
            for (int reg = 0; reg < 4; ++reg) {
                float v = fmaxf(acc[ct][reg] + cb, 0.f) * cg + cbb;
                p0[reg] += v * w20;
                p1[reg] += v * w21;
            }
        }
        for (int off = 1; off < 16; off <<= 1) {
#pragma unroll
            for (int reg = 0; reg < 4; ++reg) {
                p0[reg] += __shfl_xor(p0[reg], off);
                p1[reg] += __shfl_xor(p1[reg], off);
            }
        }
        if (m == 0) {
#pragma unroll
            for (int reg = 0; reg < 4; ++reg) {
                int row = row0 + quad * 4 + reg;
                if (row < n) {
                    out[row * 2] = p0[reg] + b2[0];
                    out[row * 2 + 1] = p1[reg] + b2[1];
                }
            }
        }
    }
}

// ---------------- host orchestration ----------------

static inline int cdiv(int a, int b) { return (a + b - 1) / b; }

extern "C" void kernel_launch(void* const* d_in, const int* in_sizes, int n_in,
                              void* d_out, int out_size, void* d_ws, size_t ws_size,
                              hipStream_t stream) {
    const float* x       = (const float*)d_in[0];
    const int*   ei      = (const int*)d_in[1];
    const float* gcn_in_w = (const float*)d_in[2];
    const float* gcn_in_b = (const float*)d_in[3];
    const float* gcn_res_w = (const float*)d_in[4];
    const float* gcn_res_b = (const float*)d_in[5];
    const float* gcn_w   = (const float*)d_in[6];
    const float* gcn_b   = (const float*)d_in[7];
    const float* gcn_bn_g = (const float*)d_in[8];
    const float* gcn_bn_b = (const float*)d_in[9];
    const float* gcn_c1w = (const float*)d_in[10];
    const float* gcn_c1b = (const float*)d_in[11];
    const float* gcn_c2w = (const float*)d_in[12];
    const float* gcn_c2b = (const float*)d_in[13];
    const float* gcn_c3w = (const float*)d_in[14];
    const float* gcn_c3b = (const float*)d_in[15];
    const float* gat_in_w = (const float*)d_in[16];
    const float* gat_in_b = (const float*)d_in[17];
    const float* gat_w   = (const float*)d_in[18];
    const float* gat_asrc = (const float*)d_in[19];
    const float* gat_adst = (const float*)d_in[20];
    const float* gat_b   = (const float*)d_in[21];
    const float* gat_bn_g = (const float*)d_in[22];
    const float* gat_bn_b = (const float*)d_in[23];
    const float* feat_imp = (const float*)d_in[24];
    const float* gat_c1w = (const float*)d_in[25];
    const float* gat_c1b = (const float*)d_in[26];
    const float* gat_cbn_g = (const float*)d_in[27];
    const float* gat_cbn_b = (const float*)d_in[28];
    const float* gat_c2w = (const float*)d_in[29];
    const float* gat_c2b = (const float*)d_in[30];
    const float* gat_c3w = (const float*)d_in[31];
    const float* gat_c3b = (const float*)d_in[32];
    const float* fin_w   = (const float*)d_in[33];
    const float* fin_b   = (const float*)d_in[34];
    const float* fin_bn_g = (const float*)d_in[35];
    const float* fin_bn_b = (const float*)d_in[36];
    const float* fin2_w  = (const float*)d_in[37];
    const float* fin2_b  = (const float*)d_in[38];

    const int N = in_sizes[0] / 64;
    const int E = in_sizes[1] / 2;
    const int EN = E + N;
    const int* esrc = ei;
    const int* edst = ei + E;

    // workspace carve (256B aligned)
    char* wp = (char*)d_ws;
    auto alloc = [&](size_t bytes) -> void* {
        void* p = (void*)wp;
        wp += (bytes + 255) & ~(size_t)255;
        return p;
    };
    int* cnt    = (int*)alloc((size_t)N * 4);
    int* rowptr = (int*)alloc((size_t)(N + 1) * 4);
    int* cursor = (int*)alloc((size_t)N * 4);
    int* bsum   = (int*)alloc((size_t)256 * 4);
    int* colidx = (int*)alloc((size_t)EN * 4);
    float* dis  = (float*)alloc((size_t)N * 4);
    float* A    = (float*)alloc((size_t)N * 128 * 4);   // gcn ping
    float* B    = (float*)alloc((size_t)N * 128 * 4);   // gcn pong
    float* G    = (float*)alloc((size_t)N * 128 * 4);   // gat ping
    float* H    = (float*)alloc((size_t)N * 128 * 4);   // gat pong
    float* R    = (float*)alloc((size_t)N * 128 * 4);   // gcn residual
    __half* Th1 = (__half*)alloc((size_t)N * 128 * 2);  // gcn fp16 table
    __half* Th2 = (__half*)alloc((size_t)N * 128 * 2);  // gat fp16 table
    float* avv  = (float*)alloc((size_t)N * 4 * 4);
    float* bvv  = (float*)alloc((size_t)N * 4 * 4);
    __half* WTin = (__half*)alloc((size_t)3 * 8192 * 2);
    __half* WTg  = (__half*)alloc((size_t)3 * 16384 * 2);
    __half* WTa  = (__half*)alloc((size_t)3 * 16384 * 2);
    __half* WTc1 = (__half*)alloc((size_t)2 * 8192 * 2);
    __half* WTc3 = (__half*)alloc((size_t)2 * 4096 * 2);
    __half* WTfin = (__half*)alloc((size_t)8192 * 2);
    __half* WTc2 = (__half*)alloc((size_t)2 * 2048 * 2);

    // ---- CSR build + all-weight transpose ----
    const int nScanB = cdiv(N, 256);
    hipMemsetAsync(cnt, 0, (size_t)N * 4, stream);
    hist_k<<<cdiv(EN, 256), 256, 0, stream>>>(edst, cnt, E, EN);
    scanA_k<<<nScanB, 256, 0, stream>>>(cnt, rowptr, bsum, N);
    scanB_k<<<1, 256, 0, stream>>>(bsum, nScanB);
    scanC_k<<<nScanB, 256, 0, stream>>>(cnt, bsum, rowptr, cursor, dis, N, EN);
    scatter_k<<<cdiv(EN, 256), 256, 0, stream>>>(esrc, edst, cursor, colidx, E, EN);
    wtx_all_k<<<624, 256, 0, stream>>>(gcn_in_w, gcn_res_w, gat_in_w, gcn_w, gat_w,
                                       gcn_c1w, gat_c1w, gcn_c3w, gat_c3w, fin_w,
                                       gcn_c2w, gat_c2w,
                                       WTin, WTg, WTa, WTc1, WTc3, WTfin, WTc2);

    const int g64r = cdiv(N, 64);    // mfma kernels: 64 rows/block
    const int gG   = cdiv(N, 16);    // gather: 16 nodes/block

    // ---- input stage: gcn_in -> A, gcn_res -> R, gat_in -> G ----
    mfma_lin3_k<<<3 * g64r, 256, 0, stream>>>(x, WTin, gcn_in_b, A, gcn_res_b, R,
                                              gat_in_b, G, N, g64r);

    // ---- 3 layers, both branches in lockstep ----
    const int heads_arr[3] = {4, 4, 1};
    float* gcur = A; float* gnxt = B;
    float* acur = G; float* anxt = H;
    for (int i = 0; i < 3; ++i) {
        int hh = heads_arr[i];
        int log2C = (hh == 4) ? 5 : 7;
        dual128_mfma_k<<<2 * g64r, 256, 0, stream>>>(gcur, WTg + (size_t)i * 16384, Th1,
                                                     acur, WTa + (size_t)i * 16384, Th2, dis,
                                                     gat_asrc + i * 128, gat_adst + i * 128,
                                                     avv, bvv, hh, N, g64r);
        fused_gather_k<<<gG, 256, 0, stream>>>(rowptr, colidx, dis,
                                               Th1, gcn_b + i * 128, gcn_bn_g + i * 128,
                                               gcn_bn_b + i * 128, (i == 1) ? R : nullptr, gnxt,
                                               Th2, avv, bvv, gat_b + i * 128,
                                               gat_bn_g + i * 128, gat_bn_b + i * 128,
                                               (i == 2) ? feat_imp : nullptr, anxt,
                                               N, hh, log2C);
        float* t = gcur; gcur = gnxt; gnxt = t;
        t = acur; acur = anxt; anxt = t;
    }
    // gcur = gcn final xp (B), acur = gat final xg (H)

    // ---- fused MLP tail: c1/c2/c3/blend/fin/fin2 in one kernel ----
    fused_tail_k<<<g64r, 256, 0, stream>>>(gcur, acur,
                                           WTc1, gcn_c1b, gat_c1b, gat_cbn_g, gat_cbn_b,
                                           WTc2, gcn_c2b, gat_c2b,
                                           WTc3, gcn_c3b, gat_c3b,
                                           WTfin, fin_b, fin_bn_g, fin_bn_b,
                                           fin2_w, fin2_b, (float*)d_out, N);
}